// Round 8
// baseline (1945.639 us; speedup 1.0000x reference)
//
#include <hip/hip_runtime.h>
#include <hip/hip_bf16.h>

// Grouped SwiGLU experts: E=8, T=2048, D_IN=2048, D_H=5632. FP32 in/out.
// r12: B-operands bypass LDS (wave-private -> global->VGPR direct, single-
// buffered, vmcnt-counted). A-only LDS ring: 3 steps x 2 halves x 16KB = 96KB,
// r7's XOR swizzle (0-conflict verified). 1 barrier/step. 16x16 MFMA, exact
// r9 accumulation order + epilogues. Cuts per-step LDS traffic 256KB->160KB.

#define NEXP 8
#define TT   2048
#define DIN  2048
#define DH   5632
#define KP   2080   // padded K pitch (elems) for X / WgT / WdT

using short8 = __attribute__((ext_vector_type(8))) short;   // 8 x bf16
using f32x4  = __attribute__((ext_vector_type(4))) float;   // MFMA acc

static __device__ __forceinline__ unsigned short f2bf(float f) {
    unsigned int i = __float_as_uint(f);
    return (unsigned short)((i + 0x7FFFu + ((i >> 16) & 1u)) >> 16);  // RNE
}
static __device__ __forceinline__ void gld16(const void* g, void* l) {
    __builtin_amdgcn_global_load_lds(
        (const __attribute__((address_space(1))) void*)g,
        (__attribute__((address_space(3))) void*)l, 16, 0, 0);
}

// ---------------------------------------------------------------------------
// Fused G/U GEMM (persistent): 11 tiles of 256x128, BK=64, 8 waves 2Mx4N.
// Per step t: [issue 8 B(t) global loads -> Gq/Dq regs] [stage A(t+2): 4 gld16
// into slot (u+2)%3] [ds_read A0 (8)] [vmcnt(4|0): B(t)+A(t+1) drained]
// [MFMA G-top,U-top] [ds_read A1 (8, slot reuse)] [MFMA U-bot,G-bot]
// [lgkmcnt(0)+schedbar] [barrier].
// ---------------------------------------------------------------------------
__global__ __launch_bounds__(512, 2) void gemm_gu(
    const unsigned short* __restrict__ Xb,   // [E][T][KP] bf16
    const unsigned short* __restrict__ Wgt,  // [E][DH][KP] bf16 (K-major)
    const unsigned short* __restrict__ Wdt,  // [E][DH][KP] bf16
    unsigned short* __restrict__ Hb)         // [E][T][DH] bf16
{
    __shared__ __align__(16) unsigned short lds[49152];  // 96 KB = 6 x 16 KB

    const int tid  = threadIdx.x;
    const int wave = tid >> 6, lane = tid & 63;
    const int l15 = lane & 15, l4 = lane >> 4;
    const int wr = wave >> 2, wc = wave & 3;     // 2M x 4N wave grid

    const int bid = blockIdx.x;                  // 256 blocks = 8 XCD * 32 CU
    const int e   = bid & 7;                     // expert == XCD
    const int cu  = bid >> 3;                    // [0,32)
    const int m0  = (cu & 7) * 256;              // constant per CU
    const int nb  = cu >> 3;                     // [0,4): n0(i) = (4i+nb)*128

    const unsigned short* Ae = Xb + (size_t)e * TT * KP + (size_t)m0 * KP;
    unsigned short* He = Hb + (size_t)e * TT * DH;

    // A stage-side lane offsets (r7 swizzle: cs = c ^ ((c>>3)&7)).
    const int c0 = tid, c1 = 512 + tid;
    const int cs0 = c0 ^ ((c0 >> 3) & 7), cs1 = c1 ^ ((c1 >> 3) & 7);
    const int row0 = cs0 >> 3, col0 = (cs0 & 7) * 8;
    const int row1 = cs1 >> 3, col1 = (cs1 & 7) * 8;
    const size_t loff0 = (size_t)row0 * KP + col0;
    const size_t loff1 = (size_t)row1 * KP + col1;
    const int wvoff = wave * 1024;

    // A read-side swizzled byte offsets within a 16KB half (r7, 0-conflict).
    int ibA[4][2];
#pragma unroll
    for (int s = 0; s < 4; ++s)
#pragma unroll
        for (int ks = 0; ks < 2; ++ks) {
            const int r = wr * 64 + s * 16 + l15;
            ibA[s][ks] = (r * 128 + ks * 64 + l4 * 16) ^ ((r & 7) << 4);
        }

    // B per-lane row pointers: lane (l15,l4) reads n-row wc*32+s*16+l15,
    // elems [kb + ks*32 + l4*8, +8).
    const size_t NSTEP = (size_t)512 * KP;
    const unsigned short* gR[2];
    const unsigned short* dR[2];
    {
        const unsigned short* Gb = Wgt + (size_t)e * DH * KP + (size_t)(nb * 128) * KP;
        const unsigned short* Db = Wdt + (size_t)e * DH * KP + (size_t)(nb * 128) * KP;
#pragma unroll
        for (int s = 0; s < 2; ++s) {
            const int r = wc * 32 + s * 16 + l15;
            gR[s] = Gb + (size_t)r * KP + l4 * 8;
            dR[s] = Db + (size_t)r * KP + l4 * 8;
        }
    }

    // acc[0..3][0..1]=G-top, acc[0..3][2..3]=U-top,
    // acc[4..7][2..3]=U-bot, acc[4..7][0..1]=G-bot.
    f32x4 acc[8][4] = {};
    short8 Aq[4][2], Gq[2][2], Dq[2][2];

    char* ldsb = (char*)lds;
    const char* ldsc = (const char*)lds;
    auto stageA2 = [&](int kk, int so) {         // both halves of one step
        gld16(Ae + kk + loff0, ldsb + so + wvoff);
        gld16(Ae + kk + loff1, ldsb + so + 8192 + wvoff);
        gld16(Ae + (size_t)128 * KP + kk + loff0, ldsb + so + 16384 + wvoff);
        gld16(Ae + (size_t)128 * KP + kk + loff1, ldsb + so + 16384 + 8192 + wvoff);
    };

    // Prologue: A(0) -> slot 0, A(1) -> slot 1.
    stageA2(0, 0);
    stageA2(64, 32768);
    asm volatile("s_waitcnt vmcnt(4)" ::: "memory");
    asm volatile("s_barrier" ::: "memory");

    int u = 0;                                   // slot of step t (mod 3)
    for (int i = 0; i < 11; ++i) {
        for (int t = 0; t < 32; ++t) {
            const int sb = u << 15;              // A0 @ sb, A1 @ sb+16384
            const int u2 = (u >= 1) ? u - 1 : u + 2;   // (u+2)%3
            const int kb = t * 64;

            // B(t) loads: 8 global -> regs.
#pragma unroll
            for (int s = 0; s < 2; ++s)
#pragma unroll
                for (int ks = 0; ks < 2; ++ks) {
                    Gq[s][ks] = *(const short8*)(gR[s] + kb + ks * 32);
                    Dq[s][ks] = *(const short8*)(dR[s] + kb + ks * 32);
                }

            // Stage A(t+2) into slot u2.
            const bool st = (i < 10) || (t + 2 < 32);
            if (st) stageA2(((t + 2) & 31) * 64, u2 << 15);

            // A0 reads.
#pragma unroll
            for (int s = 0; s < 4; ++s) {
                Aq[s][0] = *(const short8*)(ldsc + sb + ibA[s][0]);
                Aq[s][1] = *(const short8*)(ldsc + sb + ibA[s][1]);
            }

            // Drain B(t) (+ A(t+1) stage, issued last step): leave only the
            // 4 newest (this step's A-stage) in flight.
            if (st) asm volatile("s_waitcnt vmcnt(4)" ::: "memory");
            else    asm volatile("s_waitcnt vmcnt(0)" ::: "memory");
            __builtin_amdgcn_sched_barrier(0);

            __builtin_amdgcn_s_setprio(1);
#pragma unroll
            for (int m = 0; m < 4; ++m)
#pragma unroll
                for (int n = 0; n < 2; ++n) {    // G-top
                    acc[m][n] = __builtin_amdgcn_mfma_f32_16x16x32_bf16(Aq[m][0], Gq[n][0], acc[m][n], 0, 0, 0);
                    acc[m][n] = __builtin_amdgcn_mfma_f32_16x16x32_bf16(Aq[m][1], Gq[n][1], acc[m][n], 0, 0, 0);
                }
#pragma unroll
            for (int m = 0; m < 4; ++m)
#pragma unroll
                for (int n = 0; n < 2; ++n) {    // U-top
                    acc[m][2 + n] = __builtin_amdgcn_mfma_f32_16x16x32_bf16(Aq[m][0], Dq[n][0], acc[m][2 + n], 0, 0, 0);
                    acc[m][2 + n] = __builtin_amdgcn_mfma_f32_16x16x32_bf16(Aq[m][1], Dq[n][1], acc[m][2 + n], 0, 0, 0);
                }
            __builtin_amdgcn_s_setprio(0);

            // A1 reads (register reuse).
#pragma unroll
            for (int s = 0; s < 4; ++s) {
                Aq[s][0] = *(const short8*)(ldsc + sb + 16384 + ibA[s][0]);
                Aq[s][1] = *(const short8*)(ldsc + sb + 16384 + ibA[s][1]);
            }

            __builtin_amdgcn_s_setprio(1);
#pragma unroll
            for (int m = 0; m < 4; ++m)
#pragma unroll
                for (int n = 0; n < 2; ++n) {    // U-bot
                    acc[4 + m][2 + n] = __builtin_amdgcn_mfma_f32_16x16x32_bf16(Aq[m][0], Dq[n][0], acc[4 + m][2 + n], 0, 0, 0);
                    acc[4 + m][2 + n] = __builtin_amdgcn_mfma_f32_16x16x32_bf16(Aq[m][1], Dq[n][1], acc[4 + m][2 + n], 0, 0, 0);
                }
#pragma unroll
            for (int m = 0; m < 4; ++m)
#pragma unroll
                for (int n = 0; n < 2; ++n) {    // G-bot
                    acc[4 + m][n] = __builtin_amdgcn_mfma_f32_16x16x32_bf16(Aq[m][0], Gq[n][0], acc[4 + m][n], 0, 0, 0);
                    acc[4 + m][n] = __builtin_amdgcn_mfma_f32_16x16x32_bf16(Aq[m][1], Gq[n][1], acc[4 + m][n], 0, 0, 0);
                }
            __builtin_amdgcn_s_setprio(0);

            // Rule #18: this wave's ds_reads must complete before the barrier
            // (next step's stages overwrite slot u(t) region at t+1).
            asm volatile("s_waitcnt lgkmcnt(0)" ::: "memory");
            __builtin_amdgcn_sched_barrier(0);
            asm volatile("s_barrier" ::: "memory");
            u = (u >= 2) ? 0 : u + 1;
        }

        // Tile epilogue: H = silu(G)*U. C/D: col=lane&15, row=(lane>>4)*4+j.
        const int n0i = (4 * i + nb) * 128;
#pragma unroll
        for (int fm = 0; fm < 8; ++fm) {
            const int row_b = m0 + (fm >> 2) * 128 + wr * 64 + (fm & 3) * 16 + l4 * 4;
#pragma unroll
            for (int nr = 0; nr < 2; ++nr) {
                const int col = n0i + wc * 32 + nr * 16 + l15;
#pragma unroll
                for (int j = 0; j < 4; ++j) {
                    const float gv = acc[fm][nr][j];
                    const float uv = acc[fm][2 + nr][j];
                    const float h = gv / (1.f + __expf(-gv)) * uv;
                    He[(size_t)(row_b + j) * DH + col] = f2bf(h);
                }
            }
        }
#pragma unroll
        for (int m = 0; m < 8; ++m)
#pragma unroll
            for (int n = 0; n < 4; ++n)
                acc[m][n] = (f32x4){0.f, 0.f, 0.f, 0.f};
#pragma unroll
        for (int s = 0; s < 2; ++s) { gR[s] += NSTEP; dR[s] += NSTEP; }
    }
}

// ---------------------------------------------------------------------------
// Out-GEMM (persistent): 2 tiles of 256x256, BK=64, 8 waves 2Mx4N.
// Same structure: A(H) in 96KB LDS ring, B0/B1 global->regs, 1 barrier/step.
// ---------------------------------------------------------------------------
__global__ __launch_bounds__(512, 2) void gemm_out(
    const unsigned short* __restrict__ Ab,   // H [E][T][DH] bf16
    const unsigned short* __restrict__ Btb,  // WuT [E][DIN][DH] bf16
    float* __restrict__ Cf)                  // [E][T][DIN] fp32
{
    __shared__ __align__(16) unsigned short lds[49152];  // 96 KB

    const int tid  = threadIdx.x;
    const int wave = tid >> 6, lane = tid & 63;
    const int l15 = lane & 15, l4 = lane >> 4;
    const int wr = wave >> 2, wc = wave & 3;     // 2M x 4N

    const int bid = blockIdx.x;                  // 256
    const int e   = bid & 7;
    const int cu  = bid >> 3;                    // [0,32)
    const int m0  = (cu & 7) * 256;
    const int nb  = cu >> 3;                     // n0(i) = (4i+nb)*256

    const unsigned short* Ae = Ab + (size_t)e * TT * DH + (size_t)m0 * DH;

    const int c0 = tid, c1 = 512 + tid;
    const int cs0 = c0 ^ ((c0 >> 3) & 7), cs1 = c1 ^ ((c1 >> 3) & 7);
    const int row0 = cs0 >> 3, col0 = (cs0 & 7) * 8;
    const int row1 = cs1 >> 3, col1 = (cs1 & 7) * 8;
    const size_t loff0 = (size_t)row0 * DH + col0;
    const size_t loff1 = (size_t)row1 * DH + col1;
    const int wvoff = wave * 1024;

    int ibA[4][2];
#pragma unroll
    for (int s = 0; s < 4; ++s)
#pragma unroll
        for (int ks = 0; ks < 2; ++ks) {
            const int r = wr * 64 + s * 16 + l15;
            ibA[s][ks] = (r * 128 + ks * 64 + l4 * 16) ^ ((r & 7) << 4);
        }

    const size_t NSTEP = (size_t)1024 * DH;
    const unsigned short* b0R[2];
    const unsigned short* b1R[2];
    {
        const unsigned short* Bb = Btb + (size_t)e * DIN * DH + (size_t)(nb * 256) * DH;
#pragma unroll
        for (int s = 0; s < 2; ++s) {
            const int r = wc * 32 + s * 16 + l15;
            b0R[s] = Bb + (size_t)r * DH + l4 * 8;
            b1R[s] = b0R[s] + (size_t)128 * DH;
        }
    }

    f32x4 acc[8][4] = {};
    short8 Aq[4][2], B0q[2][2], B1q[2][2];

    char* ldsb = (char*)lds;
    const char* ldsc = (const char*)lds;
    auto stageA2 = [&](int kk, int so) {
        gld16(Ae + kk + loff0, ldsb + so + wvoff);
        gld16(Ae + kk + loff1, ldsb + so + 8192 + wvoff);
        gld16(Ae + (size_t)128 * DH + kk + loff0, ldsb + so + 16384 + wvoff);
        gld16(Ae + (size_t)128 * DH + kk + loff1, ldsb + so + 16384 + 8192 + wvoff);
    };

    stageA2(0, 0);
    stageA2(64, 32768);
    asm volatile("s_waitcnt vmcnt(4)" ::: "memory");
    asm volatile("s_barrier" ::: "memory");

    int u = 0;
    for (int i = 0; i < 2; ++i) {
        for (int t = 0; t < 88; ++t) {
            const int sb = u << 15;
            const int u2 = (u >= 1) ? u - 1 : u + 2;
            const int kb = t * 64;

#pragma unroll
            for (int s = 0; s < 2; ++s)
#pragma unroll
                for (int ks = 0; ks < 2; ++ks) {
                    B0q[s][ks] = *(const short8*)(b0R[s] + kb + ks * 32);
                    B1q[s][ks] = *(const short8*)(b1R[s] + kb + ks * 32);
                }

            const bool st = (i < 1) || (t + 2 < 88);
            if (st) {
                const int t2 = (t + 2 >= 88) ? t + 2 - 88 : t + 2;
                stageA2(t2 * 64, u2 << 15);
            }

#pragma unroll
            for (int s = 0; s < 4; ++s) {
                Aq[s][0] = *(const short8*)(ldsc + sb + ibA[s][0]);
                Aq[s][1] = *(const short8*)(ldsc + sb + ibA[s][1]);
            }

            if (st) asm volatile("s_waitcnt vmcnt(4)" ::: "memory");
            else    asm volatile("s_waitcnt vmcnt(0)" ::: "memory");
            __builtin_amdgcn_sched_barrier(0);

            __builtin_amdgcn_s_setprio(1);
#pragma unroll
            for (int m = 0; m < 4; ++m)
#pragma unroll
                for (int n = 0; n < 2; ++n) {    // Q00
                    acc[m][n] = __builtin_amdgcn_mfma_f32_16x16x32_bf16(Aq[m][0], B0q[n][0], acc[m][n], 0, 0, 0);
                    acc[m][n] = __builtin_amdgcn_mfma_f32_16x16x32_bf16(Aq[m][1], B0q[n][1], acc[m][n], 0, 0, 0);
                }
#pragma unroll
            for (int m = 0; m < 4; ++m)
#pragma unroll
                for (int n = 0; n < 2; ++n) {    // Q01
                    acc[m][2 + n] = __builtin_amdgcn_mfma_f32_16x16x32_bf16(Aq[m][0], B1q[n][0], acc[m][2 + n], 0, 0, 0);
                    acc[m][2 + n] = __builtin_amdgcn_mfma_f32_16x16x32_bf16(Aq[m][1], B1q[n][1], acc[m][2 + n], 0, 0, 0);
                }
            __builtin_amdgcn_s_setprio(0);

#pragma unroll
            for (int s = 0; s < 4; ++s) {
                Aq[s][0] = *(const short8*)(ldsc + sb + 16384 + ibA[s][0]);
                Aq[s][1] = *(const short8*)(ldsc + sb + 16384 + ibA[s][1]);
            }

            __builtin_amdgcn_s_setprio(1);
#pragma unroll
            for (int m = 0; m < 4; ++m)
#pragma unroll
                for (int n = 0; n < 2; ++n) {    // Q11
                    acc[4 + m][2 + n] = __builtin_amdgcn_mfma_f32_16x16x32_bf16(Aq[m][0], B1q[n][0], acc[4 + m][2 + n], 0, 0, 0);
                    acc[4 + m][2 + n] = __builtin_amdgcn_mfma_f32_16x16x32_bf16(Aq[m][1], B1q[n][1], acc[4 + m][2 + n], 0, 0, 0);
                }
#pragma unroll
            for (int m = 0; m < 4; ++m)
#pragma unroll
                for (int n = 0; n < 2; ++n) {    // Q10
                    acc[4 + m][n] = __builtin_amdgcn_mfma_f32_16x16x32_bf16(Aq[m][0], B0q[n][0], acc[4 + m][n], 0, 0, 0);
                    acc[4 + m][n] = __builtin_amdgcn_mfma_f32_16x16x32_bf16(Aq[m][1], B0q[n][1], acc[4 + m][n], 0, 0, 0);
                }
            __builtin_amdgcn_s_setprio(0);

            asm volatile("s_waitcnt lgkmcnt(0)" ::: "memory");
            __builtin_amdgcn_sched_barrier(0);
            asm volatile("s_barrier" ::: "memory");
            u = (u >= 2) ? 0 : u + 1;
        }

        // Tile epilogue: fp32 store, then zero acc.
        const int n0i = (4 * i + nb) * 256;
        float* Ce = Cf + (size_t)e * TT * DIN;
#pragma unroll
        for (int fm = 0; fm < 8; ++fm) {
            const int row_b = (fm >> 2) * 128 + wr * 64 + (fm & 3) * 16 + l4 * 4;
#pragma unroll
            for (int fn = 0; fn < 4; ++fn) {
                const int col = n0i + (fn >> 1) * 128 + wc * 32 + (fn & 1) * 16 + l15;
#pragma unroll
                for (int j = 0; j < 4; ++j)
                    Ce[(size_t)(m0 + row_b + j) * DIN + col] = acc[fm][fn][j];
            }
        }
#pragma unroll
        for (int m = 0; m < 8; ++m)
#pragma unroll
            for (int n = 0; n < 4; ++n)
                acc[m][n] = (f32x4){0.f, 0.f, 0.f, 0.f};
#pragma unroll
        for (int s = 0; s < 2; ++s) { b0R[s] += NSTEP; b1R[s] += NSTEP; }
    }
}

// out[z][C][opitch] (bf16) = convert(in[z][R][C] (f32)). 64x64 tiles.
__global__ __launch_bounds__(256) void transpose_f32_bf16(
    const float* __restrict__ in, unsigned short* __restrict__ out,
    int R, int C, int opitch, size_t ies, size_t oes)
{
    in  += (size_t)blockIdx.z * ies;
    out += (size_t)blockIdx.z * oes;
    __shared__ unsigned short t[64][65];
    const int tid = threadIdx.x;
    const int lr = tid >> 4, lc = (tid & 15) * 4;
    const int r0 = blockIdx.y * 64, c0 = blockIdx.x * 64;
#pragma unroll
    for (int i = 0; i < 4; ++i) {
        const int row = lr + i * 16;
        const float4 v = *(const float4*)(in + (size_t)(r0 + row) * C + c0 + lc);
        t[row][lc + 0] = f2bf(v.x); t[row][lc + 1] = f2bf(v.y);
        t[row][lc + 2] = f2bf(v.z); t[row][lc + 3] = f2bf(v.w);
    }
    __syncthreads();
#pragma unroll
    for (int i = 0; i < 4; ++i) {
        const int crow = lr + i * 16;
        ushort4 wv;
        wv.x = t[lc + 0][crow]; wv.y = t[lc + 1][crow];
        wv.z = t[lc + 2][crow]; wv.w = t[lc + 3][crow];
        *(ushort4*)(out + (size_t)(c0 + crow) * opitch + r0 + lc) = wv;
    }
}

// X [rows][2048] f32 -> [rows][KP] bf16 (row-padded).
__global__ __launch_bounds__(256) void conv_pad_f32_bf16(
    const float* __restrict__ in, unsigned short* __restrict__ out, int n8)
{
    int i = blockIdx.x * 256 + threadIdx.x;
    const int stride = gridDim.x * 256;
    for (; i < n8; i += stride) {
        const int row = i >> 8;                  // 256 chunks of 8 per row
        const int col = (i & 255) * 8;
        const float4 v0 = *(const float4*)(in + (size_t)row * DIN + col);
        const float4 v1 = *(const float4*)(in + (size_t)row * DIN + col + 4);
        ushort4 a, b;
        a.x = f2bf(v0.x); a.y = f2bf(v0.y); a.z = f2bf(v0.z); a.w = f2bf(v0.w);
        b.x = f2bf(v1.x); b.y = f2bf(v1.y); b.z = f2bf(v1.z); b.w = f2bf(v1.w);
        *(ushort4*)(out + (size_t)row * KP + col) = a;
        *(ushort4*)(out + (size_t)row * KP + col + 4) = b;
    }
}

extern "C" void kernel_launch(void* const* d_in, const int* in_sizes, int n_in,
                              void* d_out, int out_size, void* d_ws, size_t ws_size,
                              hipStream_t stream)
{
    const float* x  = (const float*)d_in[0];  // [E,T,DIN]
    const float* wg = (const float*)d_in[1];  // [E,DIN,DH]
    const float* wd = (const float*)d_in[2];  // [E,DIN,DH]
    const float* wu = (const float*)d_in[3];  // [E,DH,DIN]
    float* out = (float*)d_out;               // [E,T,DIN] fp32

    const size_t XSZ = (size_t)TT * KP;       // per-expert X elems (padded)
    const size_t WPSZ = (size_t)DH * KP;      // per-expert padded weight elems
    const size_t WSZ = (size_t)DIN * DH;      // per-expert WuT elems (unpadded)
    unsigned short* xb  = (unsigned short*)d_ws;      // [E] X bf16 padded  68 MB
    unsigned short* wgt = xb  + (size_t)NEXP * XSZ;   // [E] WgT / WuT     188 MB
    unsigned short* wdt = wgt + (size_t)NEXP * WPSZ;  // [E] WdT           188 MB
    unsigned short* hb  = wdt + (size_t)NEXP * WPSZ;  // [E] H             185 MB
    // total ws: ~628 MB

    // X -> bf16 padded rows
    conv_pad_f32_bf16<<<4096, 256, 0, stream>>>(x, xb, NEXP * TT * (DIN / 8));
    // WgT, WdT: [E][DH][KP] K-major padded
    transpose_f32_bf16<<<dim3(DH / 64, DIN / 64, NEXP), 256, 0, stream>>>(
        wg, wgt, DIN, DH, KP, WSZ, WPSZ);
    transpose_f32_bf16<<<dim3(DH / 64, DIN / 64, NEXP), 256, 0, stream>>>(
        wd, wdt, DIN, DH, KP, WSZ, WPSZ);
    // H = silu(X*Wg) * (X*Wd)   [E][T][DH]  — persistent fused dual-acc GEMM
    gemm_gu<<<256, 512, 0, stream>>>(xb, wgt, wdt, hb);
    // WuT: [E][DIN][DH] K-major, stride 5632 non-pow2 (reuse wgt region)
    transpose_f32_bf16<<<dim3(DIN / 64, DH / 64, NEXP), 256, 0, stream>>>(
        wu, wgt, DH, DIN, DH, WSZ, WSZ);
    // Out = H * Wu   [E][T][DIN] fp32  — persistent
    gemm_out<<<256, 512, 0, stream>>>(hb, wgt, out);
}

// Round 9
// 1258.001 us; speedup vs baseline: 1.5466x; 1.5466x over previous
//
#include <hip/hip_runtime.h>
#include <hip/hip_bf16.h>

// Grouped SwiGLU experts: E=8, T=2048, D_IN=2048, D_H=5632. FP32 in/out.
// r13: revert to r5 (best verified: 1258.7 us total; gu 712 us, 0 bank
// conflicts) after r6-r12 falsified persistence/stride/VALU/shape/LDS-bypass
// hypotheses, each at or below r5. Only riskless delta kept: Wg+Wd
// transposes merged into a single launch (outputs are contiguous in ws).

#define NEXP 8
#define TT   2048
#define DIN  2048
#define DH   5632

using short8 = __attribute__((ext_vector_type(8))) short;   // 8 x bf16
using f32x4  = __attribute__((ext_vector_type(4))) float;   // MFMA acc

static __device__ __forceinline__ unsigned short f2bf(float f) {
    unsigned int i = __float_as_uint(f);
    return (unsigned short)((i + 0x7FFFu + ((i >> 16) & 1u)) >> 16);  // RNE
}
static __device__ __forceinline__ void gld16(const void* g, void* l) {
    __builtin_amdgcn_global_load_lds(
        (const __attribute__((address_space(1))) void*)g,
        (__attribute__((address_space(3))) void*)l, 16, 0, 0);
}

// ---------------------------------------------------------------------------
// Fused G/U GEMM: computes G = X*WgT^T, U = X*WdT^T, writes H = silu(G)*U.
// Tile 256(M) x 128(N), BK=64. 8 waves as 2M x 4N per quadrant (64x32 each).
// Quadrant schedule: P0: read A0(8)+Gq(4), MFMA G-top; P1: read Dq(4),
// MFMA U-top; P2: read A1(8), MFMA U-bot; P3: no reads, MFMA G-bot.
// Ring-8 16KB halves, vmcnt(6)/tile. Swizzle: read byte ^= (row&7)<<4;
// stage pre-applies c ^= (c>>3)&7. Block map: e = bid&7 (XCD), w = bid>>3.
// ---------------------------------------------------------------------------
__global__ __launch_bounds__(512, 2) void gemm_gu(
    const unsigned short* __restrict__ Xb,   // [E][T][DIN] bf16
    const unsigned short* __restrict__ Wgt,  // [E][DH][DIN] bf16 (K-major)
    const unsigned short* __restrict__ Wdt,  // [E][DH][DIN] bf16
    unsigned short* __restrict__ Hb)         // [E][T][DH] bf16
{
    __shared__ __align__(16) unsigned short lds[65536];  // 128 KB

    const int tid  = threadIdx.x;
    const int wave = tid >> 6, lane = tid & 63;
    const int l15 = lane & 15, l4 = lane >> 4;
    const int wr = wave >> 2, wc = wave & 3;     // 2M x 4N wave grid

    const int orig = blockIdx.x;                 // 2816 blocks = 8 * 352
    const int e    = orig & 7;                   // expert == XCD
    const int w    = orig >> 3;                  // [0,352)
    const int r32  = w & 31;
    const int m0   = (r32 & 7) * 256;            // 8 M-blocks
    const int n0   = ((w >> 5) * 4 + (r32 >> 3)) * 128;  // 44 N-blocks

    const int K = DIN, NT = DIN >> 6;            // NT = 32

    const unsigned short* Ae = Xb  + (size_t)e * TT * DIN;              // [T][K]
    const unsigned short* Gp = Wgt + (size_t)e * DH * DIN + (size_t)n0 * K;
    const unsigned short* Dp = Wdt + (size_t)e * DH * DIN + (size_t)n0 * K;

    // Stage-side: chunk c of 1024 16B-chunks/half; src pos cs = c ^ ((c>>3)&7).
    const int c0 = tid, c1 = 512 + tid;
    const int cs0 = c0 ^ ((c0 >> 3) & 7), cs1 = c1 ^ ((c1 >> 3) & 7);
    const int row0 = cs0 >> 3, col0 = (cs0 & 7) * 8;
    const int row1 = cs1 >> 3, col1 = (cs1 & 7) * 8;

    // Read-side swizzled byte offsets within a 16KB half.
    int ibA[4][2], ibB[2][2];
#pragma unroll
    for (int s = 0; s < 4; ++s)
#pragma unroll
        for (int ks = 0; ks < 2; ++ks) {
            const int r = wr * 64 + s * 16 + l15;
            ibA[s][ks] = (r * 128 + ks * 64 + l4 * 16) ^ ((r & 7) << 4);
        }
#pragma unroll
    for (int s = 0; s < 2; ++s)
#pragma unroll
        for (int ks = 0; ks < 2; ++ks) {
            const int r = wc * 32 + s * 16 + l15;
            ibB[s][ks] = (r * 128 + ks * 64 + l4 * 16) ^ ((r & 7) << 4);
        }

    // acc[0..3][0..1] = G-top, acc[0..3][2..3] = U-top,
    // acc[4..7][2..3] = U-bot, acc[4..7][0..1] = G-bot.
    f32x4 acc[8][4] = {};
    short8 Aq[4][2], Gq[2][2], Dq[2][2];

    auto stageA = [&](int ro, int kk, int slot) {
        gld16(Ae + (size_t)(m0 + ro + row0) * K + (kk + col0), &lds[slot * 8192 + wave * 512]);
        gld16(Ae + (size_t)(m0 + ro + row1) * K + (kk + col1), &lds[slot * 8192 + 4096 + wave * 512]);
    };
    auto stageW = [&](const unsigned short* p, int kk, int slot) {
        gld16(p + (size_t)row0 * K + (kk + col0), &lds[slot * 8192 + wave * 512]);
        gld16(p + (size_t)row1 * K + (kk + col1), &lds[slot * 8192 + 4096 + wave * 512]);
    };

    // Prologue: t0 {A0,G,D,A1} -> slots 0..3; t1 {A0,G,D} -> slots 4..6.
    stageA(0, 0, 0);  stageW(Gp, 0, 1);  stageW(Dp, 0, 2);  stageA(128, 0, 3);
    stageA(0, 64, 4); stageW(Gp, 64, 5); stageW(Dp, 64, 6);
    asm volatile("s_waitcnt vmcnt(6)" ::: "memory");
    asm volatile("s_barrier" ::: "memory");

    const char* ldsc = (const char*)lds;
    for (int t = 0; t < NT; ++t) {
        const int sA0 = ((4 * t + 0) & 7) * 16384;
        const int sG  = ((4 * t + 1) & 7) * 16384;
        const int sD  = ((4 * t + 2) & 7) * 16384;
        const int sA1 = ((4 * t + 3) & 7) * 16384;

        // P0: read A0(8)+Gq(4); stage (t+1,A1); MFMA G-top
#pragma unroll
        for (int s = 0; s < 4; ++s) {
            Aq[s][0] = *(const short8*)(ldsc + sA0 + ibA[s][0]);
            Aq[s][1] = *(const short8*)(ldsc + sA0 + ibA[s][1]);
        }
#pragma unroll
        for (int s = 0; s < 2; ++s) {
            Gq[s][0] = *(const short8*)(ldsc + sG + ibB[s][0]);
            Gq[s][1] = *(const short8*)(ldsc + sG + ibB[s][1]);
        }
        if (t + 1 < NT) stageA(128, (t + 1) * 64, (4 * t + 7) & 7);
        asm volatile("s_barrier" ::: "memory");
        asm volatile("s_waitcnt lgkmcnt(0)" ::: "memory");
        __builtin_amdgcn_sched_barrier(0);
        __builtin_amdgcn_s_setprio(1);
#pragma unroll
        for (int m = 0; m < 4; ++m)
#pragma unroll
            for (int n = 0; n < 2; ++n) {
                acc[m][n] = __builtin_amdgcn_mfma_f32_16x16x32_bf16(Aq[m][0], Gq[n][0], acc[m][n], 0, 0, 0);
                acc[m][n] = __builtin_amdgcn_mfma_f32_16x16x32_bf16(Aq[m][1], Gq[n][1], acc[m][n], 0, 0, 0);
            }
        __builtin_amdgcn_s_setprio(0);
        asm volatile("s_barrier" ::: "memory");

        // P1: read Dq(4); stage (t+2,A0); MFMA U-top
#pragma unroll
        for (int s = 0; s < 2; ++s) {
            Dq[s][0] = *(const short8*)(ldsc + sD + ibB[s][0]);
            Dq[s][1] = *(const short8*)(ldsc + sD + ibB[s][1]);
        }
        if (t + 2 < NT) stageA(0, (t + 2) * 64, (4 * t + 8) & 7);
        asm volatile("s_barrier" ::: "memory");
        asm volatile("s_waitcnt lgkmcnt(0)" ::: "memory");
        __builtin_amdgcn_sched_barrier(0);
        __builtin_amdgcn_s_setprio(1);
#pragma unroll
        for (int m = 0; m < 4; ++m)
#pragma unroll
            for (int n = 0; n < 2; ++n) {
                acc[m][2 + n] = __builtin_amdgcn_mfma_f32_16x16x32_bf16(Aq[m][0], Dq[n][0], acc[m][2 + n], 0, 0, 0);
                acc[m][2 + n] = __builtin_amdgcn_mfma_f32_16x16x32_bf16(Aq[m][1], Dq[n][1], acc[m][2 + n], 0, 0, 0);
            }
        __builtin_amdgcn_s_setprio(0);
        asm volatile("s_barrier" ::: "memory");

        // P2: read A1(8); stage (t+2,G); MFMA U-bot
#pragma unroll
        for (int s = 0; s < 4; ++s) {
            Aq[s][0] = *(const short8*)(ldsc + sA1 + ibA[s][0]);
            Aq[s][1] = *(const short8*)(ldsc + sA1 + ibA[s][1]);
        }
        if (t + 2 < NT) stageW(Gp, (t + 2) * 64, (4 * t + 9) & 7);
        asm volatile("s_barrier" ::: "memory");
        asm volatile("s_waitcnt lgkmcnt(0)" ::: "memory");
        __builtin_amdgcn_sched_barrier(0);
        __builtin_amdgcn_s_setprio(1);
#pragma unroll
        for (int m = 0; m < 4; ++m)
#pragma unroll
            for (int n = 0; n < 2; ++n) {
                acc[4 + m][2 + n] = __builtin_amdgcn_mfma_f32_16x16x32_bf16(Aq[m][0], Dq[n][0], acc[4 + m][2 + n], 0, 0, 0);
                acc[4 + m][2 + n] = __builtin_amdgcn_mfma_f32_16x16x32_bf16(Aq[m][1], Dq[n][1], acc[4 + m][2 + n], 0, 0, 0);
            }
        __builtin_amdgcn_s_setprio(0);
        asm volatile("s_barrier" ::: "memory");

        // P3: stage (t+2,D); MFMA G-bot (register-only); vmcnt
        if (t + 2 < NT) stageW(Dp, (t + 2) * 64, (4 * t + 10) & 7);
        asm volatile("s_barrier" ::: "memory");
        __builtin_amdgcn_s_setprio(1);
#pragma unroll
        for (int m = 0; m < 4; ++m)
#pragma unroll
            for (int n = 0; n < 2; ++n) {
                acc[4 + m][n] = __builtin_amdgcn_mfma_f32_16x16x32_bf16(Aq[m][0], Gq[n][0], acc[4 + m][n], 0, 0, 0);
                acc[4 + m][n] = __builtin_amdgcn_mfma_f32_16x16x32_bf16(Aq[m][1], Gq[n][1], acc[4 + m][n], 0, 0, 0);
            }
        __builtin_amdgcn_s_setprio(0);
        if (t < NT - 2)       asm volatile("s_waitcnt vmcnt(6)" ::: "memory");
        else if (t == NT - 2) asm volatile("s_waitcnt vmcnt(0)" ::: "memory");
        asm volatile("s_barrier" ::: "memory");
    }

    // Epilogue: H = silu(G) * U, bf16. C/D: col = lane&15, row = (lane>>4)*4+j.
    unsigned short* He = Hb + (size_t)e * TT * DH;
#pragma unroll
    for (int fm = 0; fm < 8; ++fm) {
        const int row_b = m0 + (fm >> 2) * 128 + wr * 64 + (fm & 3) * 16 + l4 * 4;
#pragma unroll
        for (int nr = 0; nr < 2; ++nr) {
            const int col = n0 + wc * 32 + nr * 16 + l15;
#pragma unroll
            for (int j = 0; j < 4; ++j) {
                const float g = acc[fm][nr][j];
                const float u = acc[fm][2 + nr][j];
                const float h = g / (1.f + __expf(-g)) * u;
                He[(size_t)(row_b + j) * DH + col] = f2bf(h);
            }
        }
    }
}

// ---------------------------------------------------------------------------
// Out-GEMM: Out = H * WuT^T, fp32 out. 256x256, BK=64, 8 waves (2Mx4N),
// ring-8 halves {A0,B0,B1,A1}, vmcnt(6)/K-tile.
// Block map: e = bid&7, w = bid>>3 in [0,64): chunks of 8M x 4N.
// ---------------------------------------------------------------------------
__global__ __launch_bounds__(512, 2) void gemm_out(
    const unsigned short* __restrict__ Ab,   // H [E][T][DH] bf16
    const unsigned short* __restrict__ Btb,  // WuT [E][DIN][DH] bf16
    float* __restrict__ Cf)                  // [E][T][DIN] fp32
{
    __shared__ __align__(16) unsigned short lds[65536];

    const int tid  = threadIdx.x;
    const int wave = tid >> 6, lane = tid & 63;
    const int l15 = lane & 15, l4 = lane >> 4;
    const int wr = wave >> 2, wc = wave & 3;     // 2M x 4N

    const int orig = blockIdx.x;                 // 512 = 8 * 64
    const int e    = orig & 7;
    const int w    = orig >> 3;                  // [0,64)
    const int r32  = w & 31;
    const int m0   = (r32 & 7) * 256;
    const int n0   = ((w >> 5) * 4 + (r32 >> 3)) * 256;

    const int M = TT, N = DIN, K = DH, NT = K >> 6;   // NT = 88
    const unsigned short* Ae = Ab  + (size_t)e * TT * DH;
    const unsigned short* Be = Btb + (size_t)e * DIN * DH;

    const int c0 = tid, c1 = 512 + tid;
    const int cs0 = c0 ^ ((c0 >> 3) & 7), cs1 = c1 ^ ((c1 >> 3) & 7);
    const int row0 = cs0 >> 3, col0 = (cs0 & 7) * 8;
    const int row1 = cs1 >> 3, col1 = (cs1 & 7) * 8;

    int ibA[4][2], ibB[2][2];
#pragma unroll
    for (int s = 0; s < 4; ++s)
#pragma unroll
        for (int ks = 0; ks < 2; ++ks) {
            const int r = wr * 64 + s * 16 + l15;
            ibA[s][ks] = (r * 128 + ks * 64 + l4 * 16) ^ ((r & 7) << 4);
        }
#pragma unroll
    for (int s = 0; s < 2; ++s)
#pragma unroll
        for (int ks = 0; ks < 2; ++ks) {
            const int r = wc * 32 + s * 16 + l15;
            ibB[s][ks] = (r * 128 + ks * 64 + l4 * 16) ^ ((r & 7) << 4);
        }

    f32x4 acc[8][4] = {};
    short8 Aq[4][2], B0q[2][2], B1q[2][2];

    auto stageA = [&](int ro, int kk, int slot) {
        gld16(Ae + (size_t)(m0 + ro + row0) * K + (kk + col0), &lds[slot * 8192 + wave * 512]);
        gld16(Ae + (size_t)(m0 + ro + row1) * K + (kk + col1), &lds[slot * 8192 + 4096 + wave * 512]);
    };
    auto stageB = [&](int co, int kk, int slot) {
        gld16(Be + (size_t)(n0 + co + row0) * K + (kk + col0), &lds[slot * 8192 + wave * 512]);
        gld16(Be + (size_t)(n0 + co + row1) * K + (kk + col1), &lds[slot * 8192 + 4096 + wave * 512]);
    };

    stageA(0, 0, 0); stageB(0, 0, 1); stageB(128, 0, 2); stageA(128, 0, 3);
    stageA(0, 64, 4); stageB(0, 64, 5); stageB(128, 64, 6);
    asm volatile("s_waitcnt vmcnt(6)" ::: "memory");
    asm volatile("s_barrier" ::: "memory");

    const char* ldsc = (const char*)lds;
    for (int t = 0; t < NT; ++t) {
        const int sA0 = ((4 * t + 0) & 7) * 16384;
        const int sB0 = ((4 * t + 1) & 7) * 16384;
        const int sB1 = ((4 * t + 2) & 7) * 16384;
        const int sA1 = ((4 * t + 3) & 7) * 16384;

        // P0: read A0(8)+B0(4); stage (t+1,A1); MFMA Q(0,0)
#pragma unroll
        for (int s = 0; s < 4; ++s) {
            Aq[s][0] = *(const short8*)(ldsc + sA0 + ibA[s][0]);
            Aq[s][1] = *(const short8*)(ldsc + sA0 + ibA[s][1]);
        }
#pragma unroll
        for (int s = 0; s < 2; ++s) {
            B0q[s][0] = *(const short8*)(ldsc + sB0 + ibB[s][0]);
            B0q[s][1] = *(const short8*)(ldsc + sB0 + ibB[s][1]);
        }
        if (t + 1 < NT) stageA(128, (t + 1) * 64, (4 * t + 7) & 7);
        asm volatile("s_barrier" ::: "memory");
        asm volatile("s_waitcnt lgkmcnt(0)" ::: "memory");
        __builtin_amdgcn_sched_barrier(0);
        __builtin_amdgcn_s_setprio(1);
#pragma unroll
        for (int m = 0; m < 4; ++m)
#pragma unroll
            for (int n = 0; n < 2; ++n) {
                acc[m][n] = __builtin_amdgcn_mfma_f32_16x16x32_bf16(Aq[m][0], B0q[n][0], acc[m][n], 0, 0, 0);
                acc[m][n] = __builtin_amdgcn_mfma_f32_16x16x32_bf16(Aq[m][1], B0q[n][1], acc[m][n], 0, 0, 0);
            }
        __builtin_amdgcn_s_setprio(0);
        asm volatile("s_barrier" ::: "memory");

        // P1: read B1(4); stage (t+2,A0); MFMA Q(0,1)
#pragma unroll
        for (int s = 0; s < 2; ++s) {
            B1q[s][0] = *(const short8*)(ldsc + sB1 + ibB[s][0]);
            B1q[s][1] = *(const short8*)(ldsc + sB1 + ibB[s][1]);
        }
        if (t + 2 < NT) stageA(0, (t + 2) * 64, (4 * t + 8) & 7);
        asm volatile("s_barrier" ::: "memory");
        asm volatile("s_waitcnt lgkmcnt(0)" ::: "memory");
        __builtin_amdgcn_sched_barrier(0);
        __builtin_amdgcn_s_setprio(1);
#pragma unroll
        for (int m = 0; m < 4; ++m)
#pragma unroll
            for (int n = 0; n < 2; ++n) {
                acc[m][2 + n] = __builtin_amdgcn_mfma_f32_16x16x32_bf16(Aq[m][0], B1q[n][0], acc[m][2 + n], 0, 0, 0);
                acc[m][2 + n] = __builtin_amdgcn_mfma_f32_16x16x32_bf16(Aq[m][1], B1q[n][1], acc[m][2 + n], 0, 0, 0);
            }
        __builtin_amdgcn_s_setprio(0);
        asm volatile("s_barrier" ::: "memory");

        // P2: read A1(8); stage (t+2,B0); MFMA Q(1,1)
#pragma unroll
        for (int s = 0; s < 4; ++s) {
            Aq[s][0] = *(const short8*)(ldsc + sA1 + ibA[s][0]);
            Aq[s][1] = *(const short8*)(ldsc + sA1 + ibA[s][1]);
        }
        if (t + 2 < NT) stageB(0, (t + 2) * 64, (4 * t + 9) & 7);
        asm volatile("s_barrier" ::: "memory");
        asm volatile("s_waitcnt lgkmcnt(0)" ::: "memory");
        __builtin_amdgcn_sched_barrier(0);
        __builtin_amdgcn_s_setprio(1);
#pragma unroll
        for (int m = 0; m < 4; ++m)
#pragma unroll
            for (int n = 0; n < 2; ++n) {
                acc[4 + m][2 + n] = __builtin_amdgcn_mfma_f32_16x16x32_bf16(Aq[m][0], B1q[n][0], acc[4 + m][2 + n], 0, 0, 0);
                acc[4 + m][2 + n] = __builtin_amdgcn_mfma_f32_16x16x32_bf16(Aq[m][1], B1q[n][1], acc[4 + m][2 + n], 0, 0, 0);
            }
        __builtin_amdgcn_s_setprio(0);
        asm volatile("s_barrier" ::: "memory");

        // P3: stage (t+2,B1); MFMA Q(1,0); vmcnt
        if (t + 2 < NT) stageB(128, (t + 2) * 64, (4 * t + 10) & 7);
        asm volatile("s_barrier" ::: "memory");
        __builtin_amdgcn_s_setprio(1);
#pragma unroll
        for (int m = 0; m < 4; ++m)
#pragma unroll
            for (int n = 0; n < 2; ++n) {
                acc[4 + m][n] = __builtin_amdgcn_mfma_f32_16x16x32_bf16(Aq[m][0], B0q[n][0], acc[4 + m][n], 0, 0, 0);
                acc[4 + m][n] = __builtin_amdgcn_mfma_f32_16x16x32_bf16(Aq[m][1], B0q[n][1], acc[4 + m][n], 0, 0, 0);
            }
        __builtin_amdgcn_s_setprio(0);
        if (t < NT - 2)       asm volatile("s_waitcnt vmcnt(6)" ::: "memory");
        else if (t == NT - 2) asm volatile("s_waitcnt vmcnt(0)" ::: "memory");
        asm volatile("s_barrier" ::: "memory");
    }

    float* Ce = Cf + (size_t)e * TT * DIN;
#pragma unroll
    for (int fm = 0; fm < 8; ++fm) {
        const int row_b = (fm >> 2) * 128 + wr * 64 + (fm & 3) * 16 + l4 * 4;
#pragma unroll
        for (int fn = 0; fn < 4; ++fn) {
            const int col = n0 + (fn >> 1) * 128 + wc * 32 + (fn & 1) * 16 + l15;
#pragma unroll
            for (int j = 0; j < 4; ++j)
                Ce[(size_t)(m0 + row_b + j) * N + col] = acc[fm][fn][j];
        }
    }
}

// out[z][C][R] (bf16) = convert(in_z[z&7][R][C] (f32)) where in_z selects
// in0 (z<8) or in1 (z>=8). Output indexes linearly over z (wgt|wdt are
// contiguous). 64x64 tiles.
__global__ __launch_bounds__(256) void transpose2_f32_bf16(
    const float* __restrict__ in0, const float* __restrict__ in1,
    unsigned short* __restrict__ out, int R, int C, size_t ies, size_t oes)
{
    const int z = blockIdx.z;
    const float* in = ((z < NEXP) ? in0 : in1) + (size_t)(z & 7) * ies;
    out += (size_t)z * oes;
    __shared__ unsigned short t[64][65];
    const int tid = threadIdx.x;
    const int lr = tid >> 4, lc = (tid & 15) * 4;
    const int r0 = blockIdx.y * 64, c0 = blockIdx.x * 64;
#pragma unroll
    for (int i = 0; i < 4; ++i) {
        const int row = lr + i * 16;
        const float4 v = *(const float4*)(in + (size_t)(r0 + row) * C + c0 + lc);
        t[row][lc + 0] = f2bf(v.x); t[row][lc + 1] = f2bf(v.y);
        t[row][lc + 2] = f2bf(v.z); t[row][lc + 3] = f2bf(v.w);
    }
    __syncthreads();
#pragma unroll
    for (int i = 0; i < 4; ++i) {
        const int crow = lr + i * 16;
        ushort4 wv;
        wv.x = t[lc + 0][crow]; wv.y = t[lc + 1][crow];
        wv.z = t[lc + 2][crow]; wv.w = t[lc + 3][crow];
        *(ushort4*)(out + (size_t)(c0 + crow) * R + r0 + lc) = wv;
    }
}

__global__ __launch_bounds__(256) void conv_f32_bf16(
    const float* __restrict__ in, unsigned short* __restrict__ out, int n4)
{
    int i = blockIdx.x * 256 + threadIdx.x;
    const int stride = gridDim.x * 256;
    for (; i < n4; i += stride) {
        const float4 v = ((const float4*)in)[i];
        ushort4 wv;
        wv.x = f2bf(v.x); wv.y = f2bf(v.y); wv.z = f2bf(v.z); wv.w = f2bf(v.w);
        ((ushort4*)out)[i] = wv;
    }
}

extern "C" void kernel_launch(void* const* d_in, const int* in_sizes, int n_in,
                              void* d_out, int out_size, void* d_ws, size_t ws_size,
                              hipStream_t stream)
{
    const float* x  = (const float*)d_in[0];  // [E,T,DIN]
    const float* wg = (const float*)d_in[1];  // [E,DIN,DH]
    const float* wd = (const float*)d_in[2];  // [E,DIN,DH]
    const float* wu = (const float*)d_in[3];  // [E,DH,DIN]
    float* out = (float*)d_out;               // [E,T,DIN] fp32

    const size_t XSZ = (size_t)TT * DIN;      // per-expert X elems
    const size_t WSZ = (size_t)DIN * DH;      // per-expert weight elems
    unsigned short* xb  = (unsigned short*)d_ws;      // [E] X bf16      67 MB
    unsigned short* wgt = xb  + (size_t)NEXP * XSZ;   // [E] WgT / WuT  185 MB
    unsigned short* wdt = wgt + (size_t)NEXP * WSZ;   // [E] WdT        185 MB
    unsigned short* hb  = wdt + (size_t)NEXP * WSZ;   // [E] H          185 MB
    // total ws: 622 MB

    // X -> bf16 (all experts)
    conv_f32_bf16<<<4096, 256, 0, stream>>>(x, xb, (int)(NEXP * XSZ / 4));
    // WgT + WdT in ONE launch: z in [0,16) covers wgt then wdt (contiguous).
    transpose2_f32_bf16<<<dim3(DH / 64, DIN / 64, NEXP * 2), 256, 0, stream>>>(
        wg, wd, wgt, DIN, DH, WSZ, WSZ);
    // H = silu(X*Wg) * (X*Wd)   [E][T][DH]  — fused dual-acc GEMM
    gemm_gu<<<NEXP * (TT / 256) * (DH / 128), 512, 0, stream>>>(xb, wgt, wdt, hb);
    // WuT: [E][DIN][DH] K-major (reuse WgT region)
    transpose2_f32_bf16<<<dim3(DIN / 64, DH / 64, NEXP), 256, 0, stream>>>(
        wu, wu, wgt, DH, DIN, WSZ, WSZ);
    // Out = H * Wu   [E][T][DIN] fp32
    gemm_out<<<NEXP * (TT / 256) * (DIN / 256), 512, 0, stream>>>(hb, wgt, out);
}